// Round 10
// baseline (815.381 us; speedup 1.0000x reference)
//
#include <hip/hip_runtime.h>
#include <cstdint>
#include <cstddef>

// SOM BMU: dists[b,m] = ||x[b] - W[:,m] + eps||, argmin/min over m.
//   sq = rowTerm[b] + colTerm[m] - 2*dot(x[b],W[:,m]) + D*eps^2
// dot via split-precision f16 MFMA (xh.wh + xh.wl + xl.wh, ~2^-22 rel err).
// R10 = R8 som (128x256 tile, 96 MFMA/wave/iter, single-buffer GLDS,
// pre-swizzled storage: addr16(r,c)=(r>>4)*32768+(c>>2)*1024+(c&3)*256+(r&15)*16)
// + __launch_bounds__(256,3) (3 blocks/CU: other blocks' compute covers the
//   per-iter GLDS drain)
// + 2 graph nodes total: prep (no-atomic colPart, no memset) -> som (finalize
//   folded in via device-scope completion counter).
// Key packs sq-bits (sqrt monotone; sqrt done once/row in finalize).

#define B_  2048
#define D_  1024
#define M_  16384
#define EPS_ 1e-6f

typedef _Float16 v8h __attribute__((ext_vector_type(8)));
typedef float    v4f __attribute__((ext_vector_type(4)));

static __device__ __forceinline__ unsigned long long umin64(unsigned long long a,
                                                            unsigned long long b) {
    return a < b ? a : b;
}

// swizzled 16B-chunk byte address: row r, k-chunk c (8 f16 per chunk)
static __device__ __forceinline__ size_t addr16(int r, int c) {
    return (size_t)(r >> 4) * 32768 + (size_t)(c >> 2) * 1024 +
           (size_t)(c & 3) * 256 + (size_t)(r & 15) * 16;
}

#define GLDS16(g, l)                                                            \
    __builtin_amdgcn_global_load_lds(                                           \
        (const __attribute__((address_space(1))) void*)(g),                     \
        (__attribute__((address_space(3))) void*)(l), 16, 0, 0)

// ---------- fused prep (single node, no memsets needed) ----------
// blocks 0..2047: W 128d x 64m tiles -> wth/wtl + colPart[d8][m] direct write
// blocks 2048..2303: x, 8 rows each -> xh/xl + rowTerm
// block 2304: keys init, counter=0, loss slot=0
__global__ __launch_bounds__(256) void prep(
    const float* __restrict__ x, const float* __restrict__ W,
    _Float16* __restrict__ xh, _Float16* __restrict__ xl,
    _Float16* __restrict__ wth, _Float16* __restrict__ wtl,
    float* __restrict__ rowTerm, float* __restrict__ colPart,
    unsigned long long* __restrict__ keys, unsigned int* __restrict__ cnt,
    float* __restrict__ out)
{
    const int t = threadIdx.x;
    const int blk = blockIdx.x;
    if (blk < 2048) {
        __shared__ float tile[64][65];
        const int m0 = (blk & 255) * 64;
        const int d0base = (blk >> 8) * 128;
        const int dloc = t >> 4, mq = (t & 15) * 4;
        const int mloc = t >> 2, j = t & 3;
        const int dc = j * 16;
        float part = 0.f;
        for (int half = 0; half < 2; ++half) {
            const int d0 = d0base + half * 64;
            __syncthreads();   // protect tile against overwrite
            #pragma unroll
            for (int s = 0; s < 4; ++s) {
                float4 v = *(const float4*)(W + (size_t)(d0 + dloc + 16 * s) * M_ + m0 + mq);
                tile[dloc + 16 * s][mq + 0] = v.x;
                tile[dloc + 16 * s][mq + 1] = v.y;
                tile[dloc + 16 * s][mq + 2] = v.z;
                tile[dloc + 16 * s][mq + 3] = v.w;
            }
            __syncthreads();
            v8h h0, l0, h1, l1;
            #pragma unroll
            for (int e = 0; e < 8; ++e) {
                float v = tile[dc + e][mloc];
                _Float16 hi = (_Float16)v;
                h0[e] = hi; l0[e] = (_Float16)(v - (float)hi);
                part += v * v - 2.0f * EPS_ * v;
            }
            #pragma unroll
            for (int e = 0; e < 8; ++e) {
                float v = tile[dc + 8 + e][mloc];
                _Float16 hi = (_Float16)v;
                h1[e] = hi; l1[e] = (_Float16)(v - (float)hi);
                part += v * v - 2.0f * EPS_ * v;
            }
            const int m  = m0 + mloc;
            const int c0 = (d0 >> 3) + j * 2;
            const size_t a0 = addr16(m, c0), a1 = addr16(m, c0 + 1);
            *(v8h*)((char*)wth + a0) = h0; *(v8h*)((char*)wth + a1) = h1;
            *(v8h*)((char*)wtl + a0) = l0; *(v8h*)((char*)wtl + a1) = l1;
        }
        part += __shfl_xor(part, 1, 64);
        part += __shfl_xor(part, 2, 64);
        if (j == 0) colPart[(blk >> 8) * M_ + m0 + mloc] = part;
    } else if (blk < 2304) {
        __shared__ float rsum[2];
        const int rb0 = (blk - 2048) * 8;
        for (int p = 0; p < 4; ++p) {
            if (t < 2) rsum[t] = 0.f;
            __syncthreads();
            const int r = rb0 + 2 * p + (t >> 7);
            const int c = t & 127;
            float4 q1 = *(const float4*)(x + (size_t)r * D_ + 8 * c);
            float4 q2 = *(const float4*)(x + (size_t)r * D_ + 8 * c + 4);
            float vv[8] = {q1.x, q1.y, q1.z, q1.w, q2.x, q2.y, q2.z, q2.w};
            v8h h, l;
            float part = 0.f;
            #pragma unroll
            for (int e = 0; e < 8; ++e) {
                _Float16 hi = (_Float16)vv[e];
                h[e] = hi; l[e] = (_Float16)(vv[e] - (float)hi);
                part += vv[e] * vv[e] + 2.0f * EPS_ * vv[e];
            }
            const size_t a = addr16(r, c);
            *(v8h*)((char*)xh + a) = h;
            *(v8h*)((char*)xl + a) = l;
            for (int off = 32; off; off >>= 1) part += __shfl_down(part, off, 64);
            if ((t & 63) == 0) atomicAdd(&rsum[t >> 7], part);
            __syncthreads();
            if ((t & 127) == 0) rowTerm[r] = rsum[t >> 7];
            __syncthreads();
        }
    } else {
        for (int i = t; i < B_; i += 256) keys[i] = ~0ull;
        if (t == 0) { *cnt = 0u; out[3 * B_] = 0.f; }
    }
}

// ---------- main MFMA distance GEMM + argmin + fused finalize ----------
// 128x256 block tile, 4 waves (2x2, each 64 rows x 128 cols), BK=32.
__global__ __launch_bounds__(256, 3) void som_mfma(
    const _Float16* __restrict__ xh, const _Float16* __restrict__ xl,
    const _Float16* __restrict__ wth, const _Float16* __restrict__ wtl,
    const float* __restrict__ rowTerm, const float* __restrict__ colPart,
    unsigned long long* __restrict__ keys, unsigned int* __restrict__ cnt,
    const float* __restrict__ loc, float* __restrict__ out)
{
    __shared__ __align__(16) char smem[49152];   // Ah 8K | Al 8K | Bh 16K | Bl 16K
    _Float16* Ah = (_Float16*)smem;
    _Float16* Al = (_Float16*)(smem + 8192);
    _Float16* Bh = (_Float16*)(smem + 16384);
    _Float16* Bl = (_Float16*)(smem + 32768);

    const int t = threadIdx.x;
    const int g = blockIdx.x;
    const int cb = (g >> 4) * 256;   // consecutive blocks share the B-slab
    const int rb = (g & 15) * 128;
    const int L = t & 63, w = t >> 6;
    const int wro = (w >> 1) * 64;
    const int wco = (w & 1) * 128;
    const int c16 = L & 15, kq = L >> 4;

    // staging: per call, wave wgrp covers one 16-row group (1 KB linear)
    const int wgrp = t >> 6;
    const int lane16 = (t & 63) * 16;
    const int ldsw = wgrp * 1024;                 // wave-uniform LDS base
    const size_t abase0 = (size_t)((rb >> 4) + wgrp) * 32768 + lane16;
    const size_t abase1 = abase0 + 4ull * 32768;
    const size_t bbase0 = (size_t)((cb >> 4) + wgrp) * 32768 + lane16;
    const size_t bbase1 = bbase0 + 4ull * 32768;
    const size_t bbase2 = bbase0 + 8ull * 32768;
    const size_t bbase3 = bbase0 + 12ull * 32768;

    const char* pxh = (const char*)xh;
    const char* pxl = (const char*)xl;
    const char* pwh = (const char*)wth;
    const char* pwl = (const char*)wtl;

    v4f acc[4][8];
    #pragma unroll
    for (int i = 0; i < 4; ++i)
        #pragma unroll
        for (int j = 0; j < 8; ++j) acc[i][j] = (v4f){0.f, 0.f, 0.f, 0.f};

    const int lofs = kq * 128 + c16 * 8;
    int ia[4], ibx[8];
    #pragma unroll
    for (int i = 0; i < 4; ++i) ia[i] = ((wro >> 4) + i) * 512 + lofs;
    #pragma unroll
    for (int j = 0; j < 8; ++j) ibx[j] = ((wco >> 4) + j) * 512 + lofs;

    for (int S = 0; S < 32; ++S) {
        const size_t ko = (size_t)S * 1024;
        __syncthreads();
        GLDS16(pxh + abase0 + ko, smem + ldsw);
        GLDS16(pxh + abase1 + ko, smem + 4096 + ldsw);
        GLDS16(pxl + abase0 + ko, smem + 8192 + ldsw);
        GLDS16(pxl + abase1 + ko, smem + 12288 + ldsw);
        GLDS16(pwh + bbase0 + ko, smem + 16384 + ldsw);
        GLDS16(pwh + bbase1 + ko, smem + 20480 + ldsw);
        GLDS16(pwh + bbase2 + ko, smem + 24576 + ldsw);
        GLDS16(pwh + bbase3 + ko, smem + 28672 + ldsw);
        GLDS16(pwl + bbase0 + ko, smem + 32768 + ldsw);
        GLDS16(pwl + bbase1 + ko, smem + 36864 + ldsw);
        GLDS16(pwl + bbase2 + ko, smem + 40960 + ldsw);
        GLDS16(pwl + bbase3 + ko, smem + 45056 + ldsw);
        __syncthreads();

        v8h ah[4], al4[4], bh4[4], bl4[4];
        #pragma unroll
        for (int i = 0; i < 4; ++i) {
            ah[i]  = *(const v8h*)(Ah + ia[i]);
            al4[i] = *(const v8h*)(Al + ia[i]);
        }
        #pragma unroll
        for (int j = 0; j < 4; ++j) {
            bh4[j] = *(const v8h*)(Bh + ibx[j]);
            bl4[j] = *(const v8h*)(Bl + ibx[j]);
        }
        #pragma unroll
        for (int i = 0; i < 4; ++i)
            #pragma unroll
            for (int j = 0; j < 4; ++j) {
                acc[i][j] = __builtin_amdgcn_mfma_f32_16x16x32_f16(ah[i],  bh4[j], acc[i][j], 0, 0, 0);
                acc[i][j] = __builtin_amdgcn_mfma_f32_16x16x32_f16(ah[i],  bl4[j], acc[i][j], 0, 0, 0);
                acc[i][j] = __builtin_amdgcn_mfma_f32_16x16x32_f16(al4[i], bh4[j], acc[i][j], 0, 0, 0);
            }
        #pragma unroll
        for (int j = 0; j < 4; ++j) {
            bh4[j] = *(const v8h*)(Bh + ibx[j + 4]);
            bl4[j] = *(const v8h*)(Bl + ibx[j + 4]);
        }
        #pragma unroll
        for (int i = 0; i < 4; ++i)
            #pragma unroll
            for (int j = 0; j < 4; ++j) {
                acc[i][j+4] = __builtin_amdgcn_mfma_f32_16x16x32_f16(ah[i],  bh4[j], acc[i][j+4], 0, 0, 0);
                acc[i][j+4] = __builtin_amdgcn_mfma_f32_16x16x32_f16(ah[i],  bl4[j], acc[i][j+4], 0, 0, 0);
                acc[i][j+4] = __builtin_amdgcn_mfma_f32_16x16x32_f16(al4[i], bh4[j], acc[i][j+4], 0, 0, 0);
            }
    }

    // epilogue: C/D layout col=lane&15, row=(lane>>4)*4+reg  [verified m89/m91]
    float cT[8];
    #pragma unroll
    for (int j = 0; j < 8; ++j) {
        const int col = cb + wco + j * 16 + c16;
        float s = 0.f;
        #pragma unroll
        for (int p = 0; p < 8; ++p) s += colPart[p * M_ + col];
        cT[j] = s;
    }
    const float de2 = (float)D_ * EPS_ * EPS_;
    #pragma unroll
    for (int i = 0; i < 4; ++i) {
        #pragma unroll
        for (int r = 0; r < 4; ++r) {
            int row_g = rb + wro + i * 16 + kq * 4 + r;
            float rt = rowTerm[row_g];
            unsigned long long best = ~0ull;
            #pragma unroll
            for (int j = 0; j < 8; ++j) {
                float sq = rt + cT[j] - 2.0f * acc[i][j][r] + de2;
                sq = fmaxf(sq, 0.0f);   // sq-bits: order == dist order (sqrt monotone)
                unsigned long long key =
                    ((unsigned long long)__float_as_uint(sq) << 32) |
                    (unsigned int)(cb + wco + j * 16 + c16);
                best = umin64(best, key);
            }
            #pragma unroll
            for (int m = 1; m <= 8; m <<= 1) {
                unsigned long long o =
                    (unsigned long long)__shfl_xor((long long)best, m, 64);
                best = umin64(best, o);
            }
            if (c16 == 0) atomicMin(&keys[row_g], best);
        }
    }

    // ---- fused finalize: last block to finish does the output pass ----
    __threadfence();
    __shared__ int lastFlag;
    if (t == 0) {
        unsigned int old = atomicAdd(cnt, 1u);
        lastFlag = (old == (unsigned int)(gridDim.x - 1));
    }
    __syncthreads();
    if (lastFlag) {
        __threadfence();   // acquire: see all blocks' atomicMins
        float sum = 0.f;
        for (int r = t; r < B_; r += 256) {
            unsigned long long k = atomicMin(&keys[r], ~0ull);  // coherent read
            unsigned int idx = (unsigned int)(k & 0xFFFFFFFFu);
            float sqv = __uint_as_float((unsigned int)(k >> 32));
            float dist = sqrtf(sqv);
            out[r] = (float)idx;
            out[B_ + 2 * r]     = loc[2 * idx];
            out[B_ + 2 * r + 1] = loc[2 * idx + 1];
            sum += dist;
        }
        for (int off = 32; off; off >>= 1) sum += __shfl_down(sum, off, 64);
        __shared__ float sred[4];
        if ((t & 63) == 0) sred[t >> 6] = sum;
        __syncthreads();
        if (t == 0) out[3 * B_] = (sred[0] + sred[1] + sred[2] + sred[3]) / (float)B_;
    }
}

// ---------- fallback fp32 path (used only if ws too small) ----------
__global__ void row_stats(const float* __restrict__ x, float* __restrict__ rowTerm) {
    int b = blockIdx.x;
    const float* xr = x + (size_t)b * D_;
    int t = threadIdx.x;
    float acc = 0.f;
    for (int i = t; i < D_; i += 256) {
        float v = xr[i];
        acc += v * v + 2.0f * EPS_ * v;
    }
    for (int off = 32; off; off >>= 1) acc += __shfl_down(acc, off, 64);
    __shared__ float s[4];
    if ((t & 63) == 0) s[t >> 6] = acc;
    __syncthreads();
    if (t == 0) rowTerm[b] = s[0] + s[1] + s[2] + s[3];
}

__global__ void col_stats(const float* __restrict__ w, float* __restrict__ colTerm) {
    int m = blockIdx.x * 256 + threadIdx.x;
    int d0 = blockIdx.y * 64;
    const float* p = w + (size_t)d0 * M_ + m;
    float acc = 0.f;
    #pragma unroll 8
    for (int d = 0; d < 64; ++d) {
        float v = p[(size_t)d * M_];
        acc += v * v - 2.0f * EPS_ * v;
    }
    atomicAdd(&colTerm[m], acc);
}

__global__ __launch_bounds__(256, 2) void som_gemm(
    const float* __restrict__ A, const float* __restrict__ Wt,
    const float* __restrict__ rowTerm, const float* __restrict__ colTerm,
    unsigned long long* __restrict__ keys)
{
    __shared__ float As[8][128];
    __shared__ float Bs[8][128];
    const int t  = threadIdx.x;
    const int rb = blockIdx.y * 128;
    const int cb = blockIdx.x * 128;
    const int tx = t & 15;
    const int ty = t >> 4;
    float acc[8][8];
    #pragma unroll
    for (int i = 0; i < 8; ++i)
        #pragma unroll
        for (int j = 0; j < 8; ++j) acc[i][j] = 0.f;
    const int la_row = t >> 1, la_k = (t & 1) * 4;
    const int lb_k = t >> 5, lb_n = (t & 31) * 4;
    const float* Aptr = A + (size_t)(rb + la_row) * D_ + la_k;
    const float* Bptr = Wt + (size_t)lb_k * M_ + cb + lb_n;
    for (int k0 = 0; k0 < D_; k0 += 8) {
        float4 av = *(const float4*)(Aptr + k0);
        float4 bv = *(const float4*)(Bptr + (size_t)k0 * M_);
        __syncthreads();
        As[la_k + 0][la_row] = av.x;
        As[la_k + 1][la_row] = av.y;
        As[la_k + 2][la_row] = av.z;
        As[la_k + 3][la_row] = av.w;
        *(float4*)&Bs[lb_k][lb_n] = bv;
        __syncthreads();
        #pragma unroll
        for (int k = 0; k < 8; ++k) {
            float a[8], b[8];
            #pragma unroll
            for (int i = 0; i < 8; ++i) a[i] = As[k][ty * 8 + i];
            #pragma unroll
            for (int j = 0; j < 8; ++j) b[j] = Bs[k][tx * 8 + j];
            #pragma unroll
            for (int i = 0; i < 8; ++i)
                #pragma unroll
                for (int j = 0; j < 8; ++j) acc[i][j] += a[i] * b[j];
        }
    }
    float rT[8], cT[8];
    #pragma unroll
    for (int i = 0; i < 8; ++i) rT[i] = rowTerm[rb + ty * 8 + i];
    #pragma unroll
    for (int j = 0; j < 8; ++j) cT[j] = colTerm[cb + tx * 8 + j];
    const float de2 = (float)D_ * EPS_ * EPS_;
    #pragma unroll
    for (int i = 0; i < 8; ++i) {
        unsigned long long best = ~0ull;
        #pragma unroll
        for (int j = 0; j < 8; ++j) {
            float sq = rT[i] + cT[j] - 2.0f * acc[i][j] + de2;
            sq = fmaxf(sq, 0.0f);
            float dist = sqrtf(sq);
            unsigned long long key =
                ((unsigned long long)__float_as_uint(dist) << 32) |
                (unsigned int)(cb + tx * 8 + j);
            best = umin64(best, key);
        }
        #pragma unroll
        for (int msk = 1; msk <= 8; msk <<= 1) {
            unsigned long long o = __shfl_xor((long long)best, msk, 64);
            best = umin64(best, (unsigned long long)o);
        }
        if (tx == 0) atomicMin(&keys[rb + ty * 8 + i], best);
    }
}

// ---------- finalize (fallback path only) ----------
__global__ void finalize(const unsigned long long* __restrict__ keys,
                         const float* __restrict__ loc,
                         float* __restrict__ out)
{
    int t = threadIdx.x;
    int r = blockIdx.x * 256 + t;
    unsigned long long k = keys[r];
    unsigned int idx = (unsigned int)(k & 0xFFFFFFFFu);
    float dist = __uint_as_float((unsigned int)(k >> 32));
    out[r] = (float)idx;
    out[B_ + 2 * r]     = loc[2 * idx];
    out[B_ + 2 * r + 1] = loc[2 * idx + 1];
    float sum = dist;
    for (int off = 32; off; off >>= 1) sum += __shfl_down(sum, off, 64);
    __shared__ float s[4];
    if ((t & 63) == 0) s[t >> 6] = sum;
    __syncthreads();
    if (t == 0) atomicAdd(&out[3 * B_], (s[0] + s[1] + s[2] + s[3]) / (float)B_);
}

extern "C" void kernel_launch(void* const* d_in, const int* in_sizes, int n_in,
                              void* d_out, int out_size, void* d_ws, size_t ws_size,
                              hipStream_t stream)
{
    const float* x   = (const float*)d_in[0];
    const float* w   = (const float*)d_in[1];
    const float* loc = (const float*)d_in[2];
    float* out = (float*)d_out;

    char* ws = (char*)d_ws;
    unsigned long long* keys = (unsigned long long*)ws;   // 16 KB
    float* rowTerm = (float*)(ws + (16 << 10));           //  8 KB
    unsigned int* cnt = (unsigned int*)(ws + (24 << 10)); //  4 B
    float* colPart = (float*)(ws + (32 << 10));           // 512 KB (8 x 16384)
    _Float16* xh  = (_Float16*)(ws + (1ull << 20));       //  4 MB
    _Float16* xl  = (_Float16*)(ws + (5ull << 20));       //  4 MB
    _Float16* wth = (_Float16*)(ws + (9ull << 20));       // 32 MB
    _Float16* wtl = (_Float16*)(ws + (41ull << 20));      // 32 MB
    const size_t NEED = 73ull << 20;

    if (ws_size >= NEED) {
        prep<<<2305, 256, 0, stream>>>(x, w, xh, xl, wth, wtl,
                                       rowTerm, colPart, keys, cnt, out);
        som_mfma<<<1024, 256, 0, stream>>>(
            xh, xl, wth, wtl, rowTerm, colPart, keys, cnt, loc, out);
    } else {
        float* colTerm = (float*)(ws + (32 << 10));
        hipMemsetAsync(keys, 0xFF, B_ * sizeof(unsigned long long), stream);
        hipMemsetAsync(colTerm, 0, M_ * sizeof(float), stream);
        hipMemsetAsync(out + 3 * B_, 0, sizeof(float), stream);
        row_stats<<<B_, 256, 0, stream>>>(x, rowTerm);
        col_stats<<<dim3(M_ / 256, D_ / 64), 256, 0, stream>>>(w, colTerm);
        som_gemm<<<dim3(M_ / 128, B_ / 128), 256, 0, stream>>>(
            x, w, rowTerm, colTerm, keys);
        finalize<<<8, 256, 0, stream>>>(keys, loc, out);
    }
}

// Round 11
// 372.390 us; speedup vs baseline: 2.1896x; 2.1896x over previous
//
#include <hip/hip_runtime.h>
#include <cstdint>
#include <cstddef>

// SOM BMU: dists[b,m] = ||x[b] - W[:,m] + eps||, argmin/min over m.
//   sq = rowTerm[b] + colTerm[m] - 2*dot(x[b],W[:,m]) + D*eps^2
// dot via split-precision f16 MFMA (xh.wh + xh.wl + xl.wh, ~2^-22 rel err).
// R11 = R8 som (128x256 tile, 96 MFMA/wave/iter, single-buffer GLDS,
// pre-swizzled storage, __launch_bounds__(256,2) -- (256,3) in R10 forced
// accumulator spill: VGPR 84, 1.1GB scratch writes, 4x slowdown)
// + R10's 2-node structure: prep (no-atomic colPart, no memsets) -> som
// (finalize fused via device-scope completion counter).
// Key packs sq-bits (sqrt monotone; sqrt once/row in finalize).

#define B_  2048
#define D_  1024
#define M_  16384
#define EPS_ 1e-6f

typedef _Float16 v8h __attribute__((ext_vector_type(8)));
typedef float    v4f __attribute__((ext_vector_type(4)));

static __device__ __forceinline__ unsigned long long umin64(unsigned long long a,
                                                            unsigned long long b) {
    return a < b ? a : b;
}

// swizzled 16B-chunk byte address: row r, k-chunk c (8 f16 per chunk)
static __device__ __forceinline__ size_t addr16(int r, int c) {
    return (size_t)(r >> 4) * 32768 + (size_t)(c >> 2) * 1024 +
           (size_t)(c & 3) * 256 + (size_t)(r & 15) * 16;
}

#define GLDS16(g, l)                                                            \
    __builtin_amdgcn_global_load_lds(                                           \
        (const __attribute__((address_space(1))) void*)(g),                     \
        (__attribute__((address_space(3))) void*)(l), 16, 0, 0)

// ---------- fused prep (single node, no memsets needed) ----------
// blocks 0..2047: W 128d x 64m tiles -> wth/wtl + colPart[d8][m] direct write
// blocks 2048..2303: x, 8 rows each -> xh/xl + rowTerm
// block 2304: keys init, counter=0, loss slot=0
__global__ __launch_bounds__(256) void prep(
    const float* __restrict__ x, const float* __restrict__ W,
    _Float16* __restrict__ xh, _Float16* __restrict__ xl,
    _Float16* __restrict__ wth, _Float16* __restrict__ wtl,
    float* __restrict__ rowTerm, float* __restrict__ colPart,
    unsigned long long* __restrict__ keys, unsigned int* __restrict__ cnt,
    float* __restrict__ out)
{
    const int t = threadIdx.x;
    const int blk = blockIdx.x;
    if (blk < 2048) {
        __shared__ float tile[64][65];
        const int m0 = (blk & 255) * 64;
        const int d0base = (blk >> 8) * 128;
        const int dloc = t >> 4, mq = (t & 15) * 4;
        const int mloc = t >> 2, j = t & 3;
        const int dc = j * 16;
        float part = 0.f;
        for (int half = 0; half < 2; ++half) {
            const int d0 = d0base + half * 64;
            __syncthreads();   // protect tile against overwrite
            #pragma unroll
            for (int s = 0; s < 4; ++s) {
                float4 v = *(const float4*)(W + (size_t)(d0 + dloc + 16 * s) * M_ + m0 + mq);
                tile[dloc + 16 * s][mq + 0] = v.x;
                tile[dloc + 16 * s][mq + 1] = v.y;
                tile[dloc + 16 * s][mq + 2] = v.z;
                tile[dloc + 16 * s][mq + 3] = v.w;
            }
            __syncthreads();
            v8h h0, l0, h1, l1;
            #pragma unroll
            for (int e = 0; e < 8; ++e) {
                float v = tile[dc + e][mloc];
                _Float16 hi = (_Float16)v;
                h0[e] = hi; l0[e] = (_Float16)(v - (float)hi);
                part += v * v - 2.0f * EPS_ * v;
            }
            #pragma unroll
            for (int e = 0; e < 8; ++e) {
                float v = tile[dc + 8 + e][mloc];
                _Float16 hi = (_Float16)v;
                h1[e] = hi; l1[e] = (_Float16)(v - (float)hi);
                part += v * v - 2.0f * EPS_ * v;
            }
            const int m  = m0 + mloc;
            const int c0 = (d0 >> 3) + j * 2;
            const size_t a0 = addr16(m, c0), a1 = addr16(m, c0 + 1);
            *(v8h*)((char*)wth + a0) = h0; *(v8h*)((char*)wth + a1) = h1;
            *(v8h*)((char*)wtl + a0) = l0; *(v8h*)((char*)wtl + a1) = l1;
        }
        part += __shfl_xor(part, 1, 64);
        part += __shfl_xor(part, 2, 64);
        if (j == 0) colPart[(blk >> 8) * M_ + m0 + mloc] = part;
    } else if (blk < 2304) {
        __shared__ float rsum[2];
        const int rb0 = (blk - 2048) * 8;
        for (int p = 0; p < 4; ++p) {
            if (t < 2) rsum[t] = 0.f;
            __syncthreads();
            const int r = rb0 + 2 * p + (t >> 7);
            const int c = t & 127;
            float4 q1 = *(const float4*)(x + (size_t)r * D_ + 8 * c);
            float4 q2 = *(const float4*)(x + (size_t)r * D_ + 8 * c + 4);
            float vv[8] = {q1.x, q1.y, q1.z, q1.w, q2.x, q2.y, q2.z, q2.w};
            v8h h, l;
            float part = 0.f;
            #pragma unroll
            for (int e = 0; e < 8; ++e) {
                _Float16 hi = (_Float16)vv[e];
                h[e] = hi; l[e] = (_Float16)(vv[e] - (float)hi);
                part += vv[e] * vv[e] + 2.0f * EPS_ * vv[e];
            }
            const size_t a = addr16(r, c);
            *(v8h*)((char*)xh + a) = h;
            *(v8h*)((char*)xl + a) = l;
            for (int off = 32; off; off >>= 1) part += __shfl_down(part, off, 64);
            if ((t & 63) == 0) atomicAdd(&rsum[t >> 7], part);
            __syncthreads();
            if ((t & 127) == 0) rowTerm[r] = rsum[t >> 7];
            __syncthreads();
        }
    } else {
        for (int i = t; i < B_; i += 256) keys[i] = ~0ull;
        if (t == 0) { *cnt = 0u; out[3 * B_] = 0.f; }
    }
}

// ---------- main MFMA distance GEMM + argmin + fused finalize ----------
// 128x256 block tile, 4 waves (2x2, each 64 rows x 128 cols), BK=32.
// __launch_bounds__(256,2): acc needs 128 VGPR; min-waves=3 forces spill (R10).
__global__ __launch_bounds__(256, 2) void som_mfma(
    const _Float16* __restrict__ xh, const _Float16* __restrict__ xl,
    const _Float16* __restrict__ wth, const _Float16* __restrict__ wtl,
    const float* __restrict__ rowTerm, const float* __restrict__ colPart,
    unsigned long long* __restrict__ keys, unsigned int* __restrict__ cnt,
    const float* __restrict__ loc, float* __restrict__ out)
{
    __shared__ __align__(16) char smem[49152];   // Ah 8K | Al 8K | Bh 16K | Bl 16K
    _Float16* Ah = (_Float16*)smem;
    _Float16* Al = (_Float16*)(smem + 8192);
    _Float16* Bh = (_Float16*)(smem + 16384);
    _Float16* Bl = (_Float16*)(smem + 32768);

    const int t = threadIdx.x;
    const int g = blockIdx.x;
    const int cb = (g >> 4) * 256;   // consecutive blocks share the B-slab
    const int rb = (g & 15) * 128;
    const int L = t & 63, w = t >> 6;
    const int wro = (w >> 1) * 64;
    const int wco = (w & 1) * 128;
    const int c16 = L & 15, kq = L >> 4;

    // staging: per call, wave wgrp covers one 16-row group (1 KB linear)
    const int wgrp = t >> 6;
    const int lane16 = (t & 63) * 16;
    const int ldsw = wgrp * 1024;                 // wave-uniform LDS base
    const size_t abase0 = (size_t)((rb >> 4) + wgrp) * 32768 + lane16;
    const size_t abase1 = abase0 + 4ull * 32768;
    const size_t bbase0 = (size_t)((cb >> 4) + wgrp) * 32768 + lane16;
    const size_t bbase1 = bbase0 + 4ull * 32768;
    const size_t bbase2 = bbase0 + 8ull * 32768;
    const size_t bbase3 = bbase0 + 12ull * 32768;

    const char* pxh = (const char*)xh;
    const char* pxl = (const char*)xl;
    const char* pwh = (const char*)wth;
    const char* pwl = (const char*)wtl;

    v4f acc[4][8];
    #pragma unroll
    for (int i = 0; i < 4; ++i)
        #pragma unroll
        for (int j = 0; j < 8; ++j) acc[i][j] = (v4f){0.f, 0.f, 0.f, 0.f};

    const int lofs = kq * 128 + c16 * 8;
    int ia[4], ibx[8];
    #pragma unroll
    for (int i = 0; i < 4; ++i) ia[i] = ((wro >> 4) + i) * 512 + lofs;
    #pragma unroll
    for (int j = 0; j < 8; ++j) ibx[j] = ((wco >> 4) + j) * 512 + lofs;

    for (int S = 0; S < 32; ++S) {
        const size_t ko = (size_t)S * 1024;
        __syncthreads();
        GLDS16(pxh + abase0 + ko, smem + ldsw);
        GLDS16(pxh + abase1 + ko, smem + 4096 + ldsw);
        GLDS16(pxl + abase0 + ko, smem + 8192 + ldsw);
        GLDS16(pxl + abase1 + ko, smem + 12288 + ldsw);
        GLDS16(pwh + bbase0 + ko, smem + 16384 + ldsw);
        GLDS16(pwh + bbase1 + ko, smem + 20480 + ldsw);
        GLDS16(pwh + bbase2 + ko, smem + 24576 + ldsw);
        GLDS16(pwh + bbase3 + ko, smem + 28672 + ldsw);
        GLDS16(pwl + bbase0 + ko, smem + 32768 + ldsw);
        GLDS16(pwl + bbase1 + ko, smem + 36864 + ldsw);
        GLDS16(pwl + bbase2 + ko, smem + 40960 + ldsw);
        GLDS16(pwl + bbase3 + ko, smem + 45056 + ldsw);
        __syncthreads();

        v8h ah[4], al4[4], bh4[4], bl4[4];
        #pragma unroll
        for (int i = 0; i < 4; ++i) {
            ah[i]  = *(const v8h*)(Ah + ia[i]);
            al4[i] = *(const v8h*)(Al + ia[i]);
        }
        #pragma unroll
        for (int j = 0; j < 4; ++j) {
            bh4[j] = *(const v8h*)(Bh + ibx[j]);
            bl4[j] = *(const v8h*)(Bl + ibx[j]);
        }
        #pragma unroll
        for (int i = 0; i < 4; ++i)
            #pragma unroll
            for (int j = 0; j < 4; ++j) {
                acc[i][j] = __builtin_amdgcn_mfma_f32_16x16x32_f16(ah[i],  bh4[j], acc[i][j], 0, 0, 0);
                acc[i][j] = __builtin_amdgcn_mfma_f32_16x16x32_f16(ah[i],  bl4[j], acc[i][j], 0, 0, 0);
                acc[i][j] = __builtin_amdgcn_mfma_f32_16x16x32_f16(al4[i], bh4[j], acc[i][j], 0, 0, 0);
            }
        #pragma unroll
        for (int j = 0; j < 4; ++j) {
            bh4[j] = *(const v8h*)(Bh + ibx[j + 4]);
            bl4[j] = *(const v8h*)(Bl + ibx[j + 4]);
        }
        #pragma unroll
        for (int i = 0; i < 4; ++i)
            #pragma unroll
            for (int j = 0; j < 4; ++j) {
                acc[i][j+4] = __builtin_amdgcn_mfma_f32_16x16x32_f16(ah[i],  bh4[j], acc[i][j+4], 0, 0, 0);
                acc[i][j+4] = __builtin_amdgcn_mfma_f32_16x16x32_f16(ah[i],  bl4[j], acc[i][j+4], 0, 0, 0);
                acc[i][j+4] = __builtin_amdgcn_mfma_f32_16x16x32_f16(al4[i], bh4[j], acc[i][j+4], 0, 0, 0);
            }
    }

    // epilogue: C/D layout col=lane&15, row=(lane>>4)*4+reg  [verified m89/m91]
    float cT[8];
    #pragma unroll
    for (int j = 0; j < 8; ++j) {
        const int col = cb + wco + j * 16 + c16;
        float s = 0.f;
        #pragma unroll
        for (int p = 0; p < 8; ++p) s += colPart[p * M_ + col];
        cT[j] = s;
    }
    const float de2 = (float)D_ * EPS_ * EPS_;
    #pragma unroll
    for (int i = 0; i < 4; ++i) {
        #pragma unroll
        for (int r = 0; r < 4; ++r) {
            int row_g = rb + wro + i * 16 + kq * 4 + r;
            float rt = rowTerm[row_g];
            unsigned long long best = ~0ull;
            #pragma unroll
            for (int j = 0; j < 8; ++j) {
                float sq = rt + cT[j] - 2.0f * acc[i][j][r] + de2;
                sq = fmaxf(sq, 0.0f);   // sq-bits: order == dist order (sqrt monotone)
                unsigned long long key =
                    ((unsigned long long)__float_as_uint(sq) << 32) |
                    (unsigned int)(cb + wco + j * 16 + c16);
                best = umin64(best, key);
            }
            #pragma unroll
            for (int m = 1; m <= 8; m <<= 1) {
                unsigned long long o =
                    (unsigned long long)__shfl_xor((long long)best, m, 64);
                best = umin64(best, o);
            }
            if (c16 == 0) atomicMin(&keys[row_g], best);
        }
    }

    // ---- fused finalize: last block to finish does the output pass ----
    __threadfence();
    __shared__ int lastFlag;
    if (t == 0) {
        unsigned int old = atomicAdd(cnt, 1u);
        lastFlag = (old == (unsigned int)(gridDim.x - 1));
    }
    __syncthreads();
    if (lastFlag) {
        __threadfence();   // acquire: see all blocks' atomicMins
        float sum = 0.f;
        for (int r = t; r < B_; r += 256) {
            unsigned long long k = atomicMin(&keys[r], ~0ull);  // coherent read
            unsigned int idx = (unsigned int)(k & 0xFFFFFFFFu);
            float sqv = __uint_as_float((unsigned int)(k >> 32));
            float dist = sqrtf(sqv);
            out[r] = (float)idx;
            out[B_ + 2 * r]     = loc[2 * idx];
            out[B_ + 2 * r + 1] = loc[2 * idx + 1];
            sum += dist;
        }
        for (int off = 32; off; off >>= 1) sum += __shfl_down(sum, off, 64);
        __shared__ float sred[4];
        if ((t & 63) == 0) sred[t >> 6] = sum;
        __syncthreads();
        if (t == 0) out[3 * B_] = (sred[0] + sred[1] + sred[2] + sred[3]) / (float)B_;
    }
}

// ---------- fallback fp32 path (used only if ws too small) ----------
__global__ void row_stats(const float* __restrict__ x, float* __restrict__ rowTerm) {
    int b = blockIdx.x;
    const float* xr = x + (size_t)b * D_;
    int t = threadIdx.x;
    float acc = 0.f;
    for (int i = t; i < D_; i += 256) {
        float v = xr[i];
        acc += v * v + 2.0f * EPS_ * v;
    }
    for (int off = 32; off; off >>= 1) acc += __shfl_down(acc, off, 64);
    __shared__ float s[4];
    if ((t & 63) == 0) s[t >> 6] = acc;
    __syncthreads();
    if (t == 0) rowTerm[b] = s[0] + s[1] + s[2] + s[3];
}

__global__ void col_stats(const float* __restrict__ w, float* __restrict__ colTerm) {
    int m = blockIdx.x * 256 + threadIdx.x;
    int d0 = blockIdx.y * 64;
    const float* p = w + (size_t)d0 * M_ + m;
    float acc = 0.f;
    #pragma unroll 8
    for (int d = 0; d < 64; ++d) {
        float v = p[(size_t)d * M_];
        acc += v * v - 2.0f * EPS_ * v;
    }
    atomicAdd(&colTerm[m], acc);
}

__global__ __launch_bounds__(256, 2) void som_gemm(
    const float* __restrict__ A, const float* __restrict__ Wt,
    const float* __restrict__ rowTerm, const float* __restrict__ colTerm,
    unsigned long long* __restrict__ keys)
{
    __shared__ float As[8][128];
    __shared__ float Bs[8][128];
    const int t  = threadIdx.x;
    const int rb = blockIdx.y * 128;
    const int cb = blockIdx.x * 128;
    const int tx = t & 15;
    const int ty = t >> 4;
    float acc[8][8];
    #pragma unroll
    for (int i = 0; i < 8; ++i)
        #pragma unroll
        for (int j = 0; j < 8; ++j) acc[i][j] = 0.f;
    const int la_row = t >> 1, la_k = (t & 1) * 4;
    const int lb_k = t >> 5, lb_n = (t & 31) * 4;
    const float* Aptr = A + (size_t)(rb + la_row) * D_ + la_k;
    const float* Bptr = Wt + (size_t)lb_k * M_ + cb + lb_n;
    for (int k0 = 0; k0 < D_; k0 += 8) {
        float4 av = *(const float4*)(Aptr + k0);
        float4 bv = *(const float4*)(Bptr + (size_t)k0 * M_);
        __syncthreads();
        As[la_k + 0][la_row] = av.x;
        As[la_k + 1][la_row] = av.y;
        As[la_k + 2][la_row] = av.z;
        As[la_k + 3][la_row] = av.w;
        *(float4*)&Bs[lb_k][lb_n] = bv;
        __syncthreads();
        #pragma unroll
        for (int k = 0; k < 8; ++k) {
            float a[8], b[8];
            #pragma unroll
            for (int i = 0; i < 8; ++i) a[i] = As[k][ty * 8 + i];
            #pragma unroll
            for (int j = 0; j < 8; ++j) b[j] = Bs[k][tx * 8 + j];
            #pragma unroll
            for (int i = 0; i < 8; ++i)
                #pragma unroll
                for (int j = 0; j < 8; ++j) acc[i][j] += a[i] * b[j];
        }
    }
    float rT[8], cT[8];
    #pragma unroll
    for (int i = 0; i < 8; ++i) rT[i] = rowTerm[rb + ty * 8 + i];
    #pragma unroll
    for (int j = 0; j < 8; ++j) cT[j] = colTerm[cb + tx * 8 + j];
    const float de2 = (float)D_ * EPS_ * EPS_;
    #pragma unroll
    for (int i = 0; i < 8; ++i) {
        unsigned long long best = ~0ull;
        #pragma unroll
        for (int j = 0; j < 8; ++j) {
            float sq = rT[i] + cT[j] - 2.0f * acc[i][j] + de2;
            sq = fmaxf(sq, 0.0f);
            float dist = sqrtf(sq);
            unsigned long long key =
                ((unsigned long long)__float_as_uint(dist) << 32) |
                (unsigned int)(cb + tx * 8 + j);
            best = umin64(best, key);
        }
        #pragma unroll
        for (int msk = 1; msk <= 8; msk <<= 1) {
            unsigned long long o = __shfl_xor((long long)best, msk, 64);
            best = umin64(best, (unsigned long long)o);
        }
        if (tx == 0) atomicMin(&keys[rb + ty * 8 + i], best);
    }
}

// ---------- finalize (fallback path only) ----------
__global__ void finalize(const unsigned long long* __restrict__ keys,
                         const float* __restrict__ loc,
                         float* __restrict__ out)
{
    int t = threadIdx.x;
    int r = blockIdx.x * 256 + t;
    unsigned long long k = keys[r];
    unsigned int idx = (unsigned int)(k & 0xFFFFFFFFu);
    float dist = __uint_as_float((unsigned int)(k >> 32));
    out[r] = (float)idx;
    out[B_ + 2 * r]     = loc[2 * idx];
    out[B_ + 2 * r + 1] = loc[2 * idx + 1];
    float sum = dist;
    for (int off = 32; off; off >>= 1) sum += __shfl_down(sum, off, 64);
    __shared__ float s[4];
    if ((t & 63) == 0) s[t >> 6] = sum;
    __syncthreads();
    if (t == 0) atomicAdd(&out[3 * B_], (s[0] + s[1] + s[2] + s[3]) / (float)B_);
}

extern "C" void kernel_launch(void* const* d_in, const int* in_sizes, int n_in,
                              void* d_out, int out_size, void* d_ws, size_t ws_size,
                              hipStream_t stream)
{
    const float* x   = (const float*)d_in[0];
    const float* w   = (const float*)d_in[1];
    const float* loc = (const float*)d_in[2];
    float* out = (float*)d_out;

    char* ws = (char*)d_ws;
    unsigned long long* keys = (unsigned long long*)ws;   // 16 KB
    float* rowTerm = (float*)(ws + (16 << 10));           //  8 KB
    unsigned int* cnt = (unsigned int*)(ws + (24 << 10)); //  4 B
    float* colPart = (float*)(ws + (32 << 10));           // 512 KB (8 x 16384)
    _Float16* xh  = (_Float16*)(ws + (1ull << 20));       //  4 MB
    _Float16* xl  = (_Float16*)(ws + (5ull << 20));       //  4 MB
    _Float16* wth = (_Float16*)(ws + (9ull << 20));       // 32 MB
    _Float16* wtl = (_Float16*)(ws + (41ull << 20));      // 32 MB
    const size_t NEED = 73ull << 20;

    if (ws_size >= NEED) {
        prep<<<2305, 256, 0, stream>>>(x, w, xh, xl, wth, wtl,
                                       rowTerm, colPart, keys, cnt, out);
        som_mfma<<<1024, 256, 0, stream>>>(
            xh, xl, wth, wtl, rowTerm, colPart, keys, cnt, loc, out);
    } else {
        float* colTerm = (float*)(ws + (32 << 10));
        hipMemsetAsync(keys, 0xFF, B_ * sizeof(unsigned long long), stream);
        hipMemsetAsync(colTerm, 0, M_ * sizeof(float), stream);
        hipMemsetAsync(out + 3 * B_, 0, sizeof(float), stream);
        row_stats<<<B_, 256, 0, stream>>>(x, rowTerm);
        col_stats<<<dim3(M_ / 256, D_ / 64), 256, 0, stream>>>(w, colTerm);
        som_gemm<<<dim3(M_ / 128, B_ / 128), 256, 0, stream>>>(
            x, w, rowTerm, colTerm, keys);
        finalize<<<8, 256, 0, stream>>>(keys, loc, out);
    }
}